// Round 2
// baseline (1640.487 us; speedup 1.0000x reference)
//
#include <hip/hip_runtime.h>
#include <math.h>

typedef unsigned short u16;
typedef unsigned int   u32;
using short8 = __attribute__((ext_vector_type(8))) short;
using f32x4  = __attribute__((ext_vector_type(4))) float;
using u16x4  = __attribute__((ext_vector_type(4))) unsigned short;

#define NB    256
#define CIN   2048
#define COUT  512
#define HW_N  196
#define EPS   1e-5f
#define INV_SQRT512 0.04419417382415922f

__device__ __forceinline__ float bf2f(u16 v){ return __uint_as_float(((u32)v)<<16); }
__device__ __forceinline__ u16 f2bf(float f){
  u32 u = __float_as_uint(f);
  u = (u + 0x7FFFu + ((u>>16)&1u)) >> 16;
  return (u16)u;
}
// order-preserving float<->uint for atomicMax/Min on floats
__device__ __forceinline__ u32 encf(float f){
  u32 u = __float_as_uint(f);
  return (u & 0x80000000u) ? ~u : (u | 0x80000000u);
}
__device__ __forceinline__ float decf(u32 u){
  return __uint_as_float((u & 0x80000000u) ? (u & 0x7FFFFFFFu) : ~u);
}

// ---------------- K-1: convert conv1_w (fp32) -> bf16 -----------------------
__global__ void k_w2bf(const float* __restrict__ w, u16* __restrict__ o, int n4)
{
  const int i = (blockIdx.x*256 + threadIdx.x);
  if (i < n4){
    float4 v = *reinterpret_cast<const float4*>(w + i*4);
    u16x4 r; r[0]=f2bf(v.x); r[1]=f2bf(v.y); r[2]=f2bf(v.z); r[3]=f2bf(v.w);
    *reinterpret_cast<u16x4*>(o + i*4) = r;
  }
}

// ---------------- K0: per-attribute MLPs (t1, t2) -> a_all, a2_all ----------
__global__ void k_attr_mlp(const float* __restrict__ attr_emb,
                           const float* __restrict__ t1_w, const float* __restrict__ t1_b,
                           const float* __restrict__ t2_w, const float* __restrict__ t2_b,
                           float* __restrict__ a_all, float* __restrict__ a2_all)
{
  const int ai = blockIdx.x >> 1, which = blockIdx.x & 1;
  const float* tw = which ? t2_w : t1_w;
  const float* tb = which ? t2_b : t1_b;
  float* op = which ? a2_all : a_all;
  __shared__ float at[512];
  for (int k = threadIdx.x; k < 512; k += 256) at[k] = attr_emb[ai*512 + k];
  __syncthreads();
  for (int o = threadIdx.x; o < 512; o += 256){
    const float* row = tw + o*512;
    float s = tb[o];
    for (int k = 0; k < 512; k += 4){
      float4 v = *reinterpret_cast<const float4*>(row + k);
      s += at[k]*v.x + at[k+1]*v.y + at[k+2]*v.z + at[k+3]*v.w;
    }
    op[ai*512 + o] = s / (1.f + expf(-s));   // swish: sigmoid(s)*s
  }
}

// ---------------- K1: conv1x1 GEMM (MFMA) + fused ASA/stat epilogue ---------
// per block: one b, 128 output channels. C = W[128,2048] @ F_b[2048,196]
#define LDK 40   // padded k-stride (bf16 elems) for transposed B panel
__global__ __launch_bounds__(256, 2)
void k_gemm(const float* __restrict__ feat, const int* __restrict__ cidx,
            const u16* __restrict__ wbf, const float* __restrict__ conv1_b,
            const float* __restrict__ bn_g, const float* __restrict__ bn_b,
            const float* __restrict__ bn_m, const float* __restrict__ bn_v,
            const float* __restrict__ w_s, const float* __restrict__ a_all,
            u16* __restrict__ x_out, float* __restrict__ attmap,
            float* __restrict__ chsum, u32* __restrict__ chmaxu, u32* __restrict__ chminu)
{
  const int b  = blockIdx.x >> 2;
  const int mt = blockIdx.x & 3;
  const int o_base = mt * 128;
  const int tid = threadIdx.x, lane = tid & 63, wave = tid >> 6;
  const int l15 = lane & 15, lh = lane >> 4;
  __shared__ u16 Ft[208 * LDK];     // [n padded to 208][k padded to 40]

  // zero the n-tail rows once (cols 196..207 feed masked MFMA lanes)
  for (int idx = tid; idx < 12*LDK; idx += 256) Ft[196*LDK + idx] = 0;

  f32x4 acc[2][13];
  #pragma unroll
  for (int i = 0; i < 2; ++i)
    #pragma unroll
    for (int jt = 0; jt < 13; ++jt) acc[i][jt] = f32x4{0.f,0.f,0.f,0.f};

  const float* fb = feat + (size_t)b * CIN * HW_N;

  for (int k0 = 0; k0 < CIN; k0 += 32){
    __syncthreads();
    // stage F[k0:k0+32][0:196] transposed into Ft[n][k], fp32 -> bf16 inline
    for (int idx = tid; idx < 32*98; idx += 256){
      int cc = idx / 98, n2 = idx - cc*98, n = n2*2;
      float2 vv = *reinterpret_cast<const float2*>(fb + (k0+cc)*HW_N + n);
      Ft[n*LDK + cc]     = f2bf(vv.x);
      Ft[(n+1)*LDK + cc] = f2bf(vv.y);
    }
    __syncthreads();

    short8 afrag[2];
    #pragma unroll
    for (int i = 0; i < 2; ++i){
      int o = o_base + wave*32 + i*16 + l15;
      afrag[i] = *reinterpret_cast<const short8*>(wbf + (size_t)o*CIN + k0 + lh*8);
    }
    #pragma unroll
    for (int jt = 0; jt < 13; ++jt){
      short8 bfrag = *reinterpret_cast<const short8*>(&Ft[(jt*16 + l15)*LDK + lh*8]);
      acc[0][jt] = __builtin_amdgcn_mfma_f32_16x16x32_bf16(afrag[0], bfrag, acc[0][jt], 0, 0, 0);
      acc[1][jt] = __builtin_amdgcn_mfma_f32_16x16x32_bf16(afrag[1], bfrag, acc[1][jt], 0, 0, 0);
    }
  }

  // epilogue: x = w0*acc + conv1_b ; img = tanh(bn(x)) ; stats over channels
  const float w0 = w_s[0];
  const int ci = cidx[b];
  float att_c[13], sum_c[13], max_c[13], min_c[13];
  #pragma unroll
  for (int jt = 0; jt < 13; ++jt){ att_c[jt]=0.f; sum_c[jt]=0.f; max_c[jt]=-3.4e38f; min_c[jt]=3.4e38f; }

  #pragma unroll
  for (int i = 0; i < 2; ++i){
    #pragma unroll
    for (int r = 0; r < 4; ++r){
      const int o = o_base + wave*32 + i*16 + lh*4 + r;
      const float cb = conv1_b[o];
      const float sc = bn_g[o] / sqrtf(bn_v[o] + EPS);
      const float bm = bn_m[o], bb = bn_b[o];
      const float ac = a_all[ci*512 + o];
      #pragma unroll
      for (int jt = 0; jt < 13; ++jt){
        const int col = jt*16 + l15;
        const float xv = w0 * acc[i][jt][r] + cb;
        if (col < HW_N) x_out[((size_t)b*COUT + o)*HW_N + col] = f2bf(xv);
        const float img = tanhf((xv - bm)*sc + bb);
        att_c[jt] += img * ac;
        sum_c[jt] += xv;
        max_c[jt] = fmaxf(max_c[jt], xv);
        min_c[jt] = fminf(min_c[jt], xv);
      }
    }
  }
  // combine the 4 lane-groups sharing a column (l, l^16, l^32, l^48)
  #pragma unroll
  for (int jt = 0; jt < 13; ++jt){
    #pragma unroll
    for (int off = 16; off < 64; off <<= 1){
      att_c[jt] += __shfl_xor(att_c[jt], off);
      sum_c[jt] += __shfl_xor(sum_c[jt], off);
      max_c[jt]  = fmaxf(max_c[jt], __shfl_xor(max_c[jt], off));
      min_c[jt]  = fminf(min_c[jt], __shfl_xor(min_c[jt], off));
    }
    const int col = jt*16 + l15;
    if (lane < 16 && col < HW_N){
      const int p = b*HW_N + col;
      atomicAdd(&attmap[p], att_c[jt] * INV_SQRT512);
      atomicAdd(&chsum[p],  sum_c[jt]);
      atomicMax(&chmaxu[p], encf(max_c[jt]));
      atomicMin(&chminu[p], encf(min_c[jt]));
    }
  }
}

// ---------------- K2: softmax + CBAM 7x7 conv -> per-pixel gain g -----------
__global__ void k_spatial(const float* __restrict__ attmap, const float* __restrict__ chsum,
                          const u32* __restrict__ chmaxu, const u32* __restrict__ chminu,
                          const float* __restrict__ sa_w, const float* __restrict__ w1_s,
                          float* __restrict__ g)
{
  const int b = blockIdx.x, t = threadIdx.x;
  __shared__ float sgate[HW_N], av[HW_N], mx[HW_N], saw[98], red[256];
  const float w1v = w1_s[0];

  float v = (t < HW_N) ? attmap[b*HW_N + t] : -3.4e38f;
  red[t] = v; __syncthreads();
  for (int s2 = 128; s2 > 0; s2 >>= 1){ if (t < s2) red[t] = fmaxf(red[t], red[t+s2]); __syncthreads(); }
  const float mxv = red[0]; __syncthreads();
  float e = (t < HW_N) ? expf(v - mxv) : 0.f;
  red[t] = e; __syncthreads();
  for (int s2 = 128; s2 > 0; s2 >>= 1){ if (t < s2) red[t] += red[t+s2]; __syncthreads(); }
  const float ssum = red[0]; __syncthreads();

  if (t < HW_N){
    const float s = w1v * (e / ssum);           // w1 * softmax
    sgate[t] = s;
    av[t] = s * chsum[b*HW_N + t] * (1.f/512.f);
    const float cmx = decf(chmaxu[b*HW_N + t]);
    const float cmn = decf(chminu[b*HW_N + t]);
    mx[t] = (s >= 0.f) ? s*cmx : s*cmn;
  }
  if (t < 98) saw[t] = sa_w[t];                 // [ci][ky][kx]: 0..48 avg, 49..97 max
  __syncthreads();

  if (t < HW_N){
    const int y = t / 14, x = t - y*14;
    float acc = 0.f;
    #pragma unroll
    for (int ky = 0; ky < 7; ++ky){
      const int iy = y + ky - 3;
      if ((unsigned)iy < 14u){
        #pragma unroll
        for (int kx = 0; kx < 7; ++kx){
          const int ix = x + kx - 3;
          if ((unsigned)ix < 14u){
            const int p = iy*14 + ix;
            acc += av[p]*saw[ky*7+kx] + mx[p]*saw[49 + ky*7+kx];
          }
        }
      }
    }
    g[b*HW_N + t] = sgate[t] / (1.f + expf(-acc));   // sigmoid(sa) * w1 * attn
  }
}

// ---------------- K3: xs[b,o] = sum_hw g[b,hw] * x[b,o,hw] ------------------
__global__ void k_gsum(const u16* __restrict__ x, const float* __restrict__ g,
                       float* __restrict__ xs)
{
  const int b = blockIdx.x, t = threadIdx.x;
  const int lane = t & 63, wave = t >> 6;
  __shared__ float gl[HW_N];
  if (t < HW_N) gl[t] = g[b*HW_N + t];
  __syncthreads();
  const u16* xb = x + (size_t)b * COUT * HW_N;
  for (int ii = 0; ii < 128; ++ii){
    const int o = wave*128 + ii;
    const u16* row = xb + (size_t)o * HW_N;
    float p = gl[lane]      * bf2f(row[lane])
            + gl[lane+64]   * bf2f(row[lane+64])
            + gl[lane+128]  * bf2f(row[lane+128]);
    if (lane < 4) p += gl[192+lane] * bf2f(row[192+lane]);
    #pragma unroll
    for (int off = 32; off > 0; off >>= 1) p += __shfl_xor(p, off);
    if (lane == 0) xs[b*COUT + o] = p;
  }
}

// ---------------- K4: ACA fc1/fc2 + mask + L2 norm -> out -------------------
__global__ void k_aca(const float* __restrict__ xs, const float* __restrict__ a2_all,
                      const int* __restrict__ cidx,
                      const float* __restrict__ fc1_w, const float* __restrict__ fc1_b,
                      const float* __restrict__ fc2_w, const float* __restrict__ fc2_b,
                      const float* __restrict__ w2_s, const float* __restrict__ masks_w,
                      float* __restrict__ out)
{
  const int b = blockIdx.x, t = threadIdx.x;
  __shared__ float cat[1024], m1[512], red[256];
  const int ci = cidx[b];
  for (int k = t; k < 512; k += 256){
    cat[k]       = xs[b*COUT + k];
    cat[512 + k] = a2_all[ci*512 + k];
  }
  __syncthreads();
  #pragma unroll
  for (int jj = 0; jj < 2; ++jj){
    const int j = t + jj*256;
    const float* row = fc1_w + (size_t)j*1024;
    float s = fc1_b[j];
    for (int k = 0; k < 1024; k += 4){
      float4 v = *reinterpret_cast<const float4*>(row + k);
      s += cat[k]*v.x + cat[k+1]*v.y + cat[k+2]*v.z + cat[k+3]*v.w;
    }
    m1[j] = fmaxf(s, 0.f);
  }
  __syncthreads();
  const float w2v = w2_s[0];
  float vout[2];
  #pragma unroll
  for (int jj = 0; jj < 2; ++jj){
    const int j = t + jj*256;
    const float* row = fc2_w + (size_t)j*512;
    float s = fc2_b[j];
    for (int k = 0; k < 512; k += 4){
      float4 v = *reinterpret_cast<const float4*>(row + k);
      s += m1[k]*v.x + m1[k+1]*v.y + m1[k+2]*v.z + m1[k+3]*v.w;
    }
    const float mm = 1.f / (1.f + expf(-s));
    const float msk = fmaxf(masks_w[ci*512 + j], 0.f);
    vout[jj] = cat[j] * w2v * mm * msk;
  }
  red[t] = vout[0]*vout[0] + vout[1]*vout[1];
  __syncthreads();
  for (int s2 = 128; s2 > 0; s2 >>= 1){ if (t < s2) red[t] += red[t+s2]; __syncthreads(); }
  const float inv = 1.f / sqrtf(red[0]);
  out[b*COUT + t]       = vout[0]*inv;
  out[b*COUT + t + 256] = vout[1]*inv;
}

// ---------------------------------------------------------------------------
extern "C" void kernel_launch(void* const* d_in, const int* in_sizes, int n_in,
                              void* d_out, int out_size, void* d_ws, size_t ws_size,
                              hipStream_t stream)
{
  const float* feat    = (const float*)d_in[0];
  const int*   cidx    = (const int*)d_in[1];
  const float* attr_emb= (const float*)d_in[2];
  const float* t1_w    = (const float*)d_in[3];
  const float* t1_b    = (const float*)d_in[4];
  const float* conv1_w = (const float*)d_in[5];
  const float* conv1_b = (const float*)d_in[6];
  const float* bn_g    = (const float*)d_in[7];
  const float* bn_b    = (const float*)d_in[8];
  const float* bn_m    = (const float*)d_in[9];
  const float* bn_v    = (const float*)d_in[10];
  const float* sa_w    = (const float*)d_in[11];
  const float* t2_w    = (const float*)d_in[12];
  const float* t2_b    = (const float*)d_in[13];
  const float* fc1_w   = (const float*)d_in[14];
  const float* fc1_b   = (const float*)d_in[15];
  const float* fc2_w   = (const float*)d_in[16];
  const float* fc2_b   = (const float*)d_in[17];
  const float* w_s     = (const float*)d_in[18];
  const float* w1_s    = (const float*)d_in[19];
  const float* w2_s    = (const float*)d_in[20];
  const float* masks_w = (const float*)d_in[21];
  float* out = (float*)d_out;

  char* ws = (char*)d_ws;
  const size_t OFF_W    = 0;                        // 512*2048*2 = 2,097,152
  const size_t OFF_X    = 2097152;                  // 256*512*196*2 = 51,380,224
  const size_t OFF_ATT  = OFF_X    + 51380224;      // 200,704 f32 bytes
  const size_t OFF_CHS  = OFF_ATT  + 200704;
  const size_t OFF_CMAX = OFF_CHS  + 200704;
  const size_t OFF_CMIN = OFF_CMAX + 200704;
  const size_t OFF_G    = OFF_CMIN + 200704;
  const size_t OFF_XS   = OFF_G    + 200704;        // 524,288 bytes
  const size_t OFF_A    = OFF_XS   + 524288;
  const size_t OFF_A2   = OFF_A    + 16384;

  u16*  wbf     = (u16*) (ws + OFF_W);
  u16*  x_buf   = (u16*) (ws + OFF_X);
  float* attmap = (float*)(ws + OFF_ATT);
  float* chsum  = (float*)(ws + OFF_CHS);
  u32*  chmaxu  = (u32*) (ws + OFF_CMAX);
  u32*  chminu  = (u32*) (ws + OFF_CMIN);
  float* gbuf   = (float*)(ws + OFF_G);
  float* xsbuf  = (float*)(ws + OFF_XS);
  float* a_all  = (float*)(ws + OFF_A);
  float* a2_all = (float*)(ws + OFF_A2);

  // attmap + chsum + chmaxu zeroed; chminu -> 0xFFFFFFFF (enc sentinel)
  hipMemsetAsync(ws + OFF_ATT, 0, 3*200704, stream);
  hipMemsetAsync(ws + OFF_CMIN, 0xFF, 200704, stream);

  k_w2bf<<<1024, 256, 0, stream>>>(conv1_w, wbf, (COUT*CIN)/4);
  k_attr_mlp<<<16, 256, 0, stream>>>(attr_emb, t1_w, t1_b, t2_w, t2_b, a_all, a2_all);
  k_gemm<<<NB*4, 256, 0, stream>>>(feat, cidx, wbf, conv1_b, bn_g, bn_b, bn_m, bn_v,
                                   w_s, a_all, x_buf, attmap, chsum, chmaxu, chminu);
  k_spatial<<<NB, 256, 0, stream>>>(attmap, chsum, chmaxu, chminu, sa_w, w1_s, gbuf);
  k_gsum<<<NB, 256, 0, stream>>>(x_buf, gbuf, xsbuf);
  k_aca<<<NB, 256, 0, stream>>>(xsbuf, a2_all, cidx, fc1_w, fc1_b, fc2_w, fc2_b,
                                w2_s, masks_w, out);
}